// Round 4
// baseline (1553.967 us; speedup 1.0000x reference)
//
#include <hip/hip_runtime.h>

// RandomMFGL: out[o][g] = (1/4) * sum_n [ (A[n] @ x) @ W[n] + b[n] ]
// A: [4][4096][16384] fp32 = 1.07 GB streamed once -> HBM-bound, floor ~175us.
//
// v3b (third submit; rounds 2-3 were container failures, kernel never ran;
// source re-audited twice for OOB/alignment/barrier faults - none found;
// this submit drops the launch_bounds min-waves request and simplifies
// prefetch addressing, zero behavioral change to the experiment):
// v1 (s_load x) == v2 (LDS x) timing proved x-delivery is NOT the
// bottleneck; the invariant A-path is. Row-per-lane direct loads scatter each
// wave instruction into 64 x 16B requests at 64KB stride (zero coalescing,
// ~1.5 TB/s effective). Now A is staged through LDS with wave-COALESCED
// global loads (8 threads/row x float4 = contiguous 128B line granules,
// 8 full lines per wave instruction), register-prefetched one tile ahead so
// HBM latency hides under the 1024-cyc FMA stage. Compute reads the lane's
// own row from LDS (pad 32->36 floats: bank-spread, BW-floor). x stays on
// the scalar path (wave-uniform s_load, proven fine by v1==v2).
// Split-K=32 partials, then tree-reduce + W/b/mean epilogue.

#define N_ENS 4
#define N_OUT 4096
#define N_IN  16384
#define ROWS  (N_ENS * N_OUT)      // 16384 rows (row = n*4096 + o)
#define GSPLIT 32                  // split-K factor
#define ICHUNK (N_IN / GSPLIT)     // 512 i per (row, split)
#define TI     32                  // i per LDS tile
#define NSTAGE (ICHUNK / TI)       // 16 stages
#define LDP    36                  // padded LDS row stride (floats)

// ---------------- kernel 1: hp[split][row][f] = sum_{i in chunk} A[row][i] * x[i][f] ----------------
__global__ __launch_bounds__(256) void k_main(const float* __restrict__ A,
                                              const float* __restrict__ x,
                                              float* __restrict__ hp) {
    const int split  = blockIdx.x & (GSPLIT - 1);   // 0..31
    const int rowblk = blockIdx.x >> 5;             // 0..63
    const int tid    = threadIdx.x;
    const int i0     = split * ICHUNK;

    __shared__ float As_lds[256 * LDP];             // 36 KB -> 4 blocks/CU (LDS-capped)

    // staging role: 8 threads per row, float4 each -> 128 B contiguous per row
    const int srow = tid >> 3;                      // 0..31 (plus p*32)
    const int sq   = tid & 7;                       // quad within the 128 B
    // this thread's fixed staging address for p=0, advanced by TI each stage
    const float* Ast = A + (size_t)(rowblk * 256 + srow) * N_IN + i0 + sq * 4;

    float acc[16];
#pragma unroll
    for (int f = 0; f < 16; ++f) acc[f] = 0.0f;

    // prologue: load tile 0 into registers (coalesced, 8 x 128B-granule insts)
    float4 pre[8];
#pragma unroll
    for (int p = 0; p < 8; ++p)
        pre[p] = *(const float4*)(Ast + (size_t)(p * 32) * N_IN);

    for (int s = 0; s < NSTAGE; ++s) {
        __syncthreads();                            // previous compute done
#pragma unroll
        for (int p = 0; p < 8; ++p)
            *(float4*)&As_lds[(p * 32 + srow) * LDP + sq * 4] = pre[p];
        __syncthreads();

        // issue next tile's global loads now; they complete under this
        // stage's compute (~1024 cyc of FMA issue vs ~900 cyc HBM latency)
        if (s + 1 < NSTAGE) {
            const float* An = Ast + (s + 1) * TI;
#pragma unroll
            for (int p = 0; p < 8; ++p)
                pre[p] = *(const float4*)(An + (size_t)(p * 32) * N_IN);
        }

        // compute: lane owns row tid; A from LDS (b128, bank-spread by pad),
        // x wave-uniform -> scalar loads feeding FMA directly
        const float* xp = x + ((size_t)i0 + s * TI) * 16;
        float4 a4[8];
#pragma unroll
        for (int q = 0; q < 8; ++q)
            a4[q] = *(const float4*)&As_lds[tid * LDP + q * 4];
        const float* af = (const float*)a4;
#pragma unroll
        for (int ii = 0; ii < TI; ++ii) {
            const float av = af[ii];
#pragma unroll
            for (int f = 0; f < 16; ++f)
                acc[f] = fmaf(av, xp[ii * 16 + f], acc[f]);
        }
    }

    const int row = rowblk * 256 + tid;
    float* outp = hp + ((size_t)split * ROWS + row) * 16;   // 64 B per lane, contiguous
#pragma unroll
    for (int f = 0; f < 16; ++f) outp[f] = acc[f];
}

// ---------------- kernel 2: h[row][f] = sum_split hp[split][row][f] (float4-vectorized) ----------------
__global__ __launch_bounds__(256) void k_hsum(const float4* __restrict__ hp,
                                              float4* __restrict__ h) {
    int t = blockIdx.x * 256 + threadIdx.x;   // 0 .. 65535 float4s
    float4 s; s.x = 0.f; s.y = 0.f; s.z = 0.f; s.w = 0.f;
#pragma unroll
    for (int sp = 0; sp < GSPLIT; ++sp) {
        float4 v = hp[(size_t)sp * (ROWS * 4) + t];
        s.x += v.x; s.y += v.y; s.z += v.z; s.w += v.w;
    }
    h[t] = s;
}

// ---------------- kernel 3: out[o][g] = 0.25 * sum_n (sum_f h[n][o][f]*W[n][f][g] + b[n][g]) ----------------
__global__ __launch_bounds__(256) void k_out(const float* __restrict__ h,
                                             const float* __restrict__ Ws,
                                             const float* __restrict__ bs,
                                             float* __restrict__ out) {
    __shared__ float Wsm[N_ENS * 16 * 16];
    __shared__ float bsm[N_ENS * 16];
    int tid = threadIdx.x;
#pragma unroll
    for (int r = 0; r < 4; ++r) Wsm[tid + 256 * r] = Ws[tid + 256 * r];
    if (tid < 64) bsm[tid] = bs[tid];
    __syncthreads();

    int idx = blockIdx.x * 256 + tid;   // 0..65535
    int o = idx >> 4;
    int gg = idx & 15;
    float s = 0.0f;
#pragma unroll
    for (int n = 0; n < N_ENS; ++n) {
        const float* hr = h + ((size_t)(n * N_OUT + o) << 4);
        float t = 0.0f;
#pragma unroll
        for (int f = 0; f < 16; ++f)
            t = fmaf(hr[f], Wsm[n * 256 + f * 16 + gg], t);
        s += t + bsm[n * 16 + gg];
    }
    out[idx] = 0.25f * s;
}

extern "C" void kernel_launch(void* const* d_in, const int* in_sizes, int n_in,
                              void* d_out, int out_size, void* d_ws, size_t ws_size,
                              hipStream_t stream) {
    const float* x  = (const float*)d_in[0];   // [1, 16384, 16]
    const float* As = (const float*)d_in[1];   // [4, 4096, 16384]
    const float* Ws = (const float*)d_in[2];   // [4, 16, 16]
    const float* bs = (const float*)d_in[3];   // [4, 16]
    float* out = (float*)d_out;                // [1, 4096, 16]

    float* hp = (float*)d_ws;                                     // 32 MB: [32][16384][16]
    float* h  = (float*)((char*)d_ws + (size_t)32 * 1024 * 1024); // 1 MB: [16384][16]

    // hp/h are fully overwritten every call -> no memset needed despite 0xAA poison.
    k_main<<<64 * GSPLIT, 256, 0, stream>>>(As, x, hp);
    k_hsum<<<(ROWS * 16 / 4) / 256, 256, 0, stream>>>((const float4*)hp, (float4*)h);
    k_out<<<(N_OUT * 16) / 256, 256, 0, stream>>>(h, Ws, bs, out);
}